// Round 3
// baseline (710.931 us; speedup 1.0000x reference)
//
#include <hip/hip_runtime.h>

#define BQ 256
#define NK 131072
#define DIM 128
#define KT2 128                  // keys per block (p1)
#define NCH2 (NK / KT2)          // 1024 blocks
#define DELTA 1e-3f

#define NB 8192                  // radix bins (float bits >> 18)
#define SHIFT 18
#define CAP 2048

typedef __attribute__((ext_vector_type(8))) short bf16x8;
typedef __attribute__((ext_vector_type(4))) float f32x4;

__device__ __forceinline__ unsigned short f2bf(float x) {
    unsigned u = __float_as_uint(x);
    u += 0x7fffu + ((u >> 16) & 1u);
    return (unsigned short)(u >> 16);
}
__device__ __forceinline__ float bf2f(unsigned short h) {
    return __uint_as_float(((unsigned)h) << 16);
}

// ---------------- p0: query squared norms ----------------
__global__ __launch_bounds__(256, 4)
void p0_qsq(const float* __restrict__ qkey, float* __restrict__ qsqg)
{
    const int t = threadIdx.x;
    #pragma unroll 1
    for (int p = 0; p < 16; ++p) {
        int r  = p * 16 + (t >> 4);
        int d0 = (t & 15) * 8;
        const float* src = qkey + (r << 7) + d0;
        float4 a = *(const float4*)src, b = *(const float4*)(src + 4);
        float s = (a.x*a.x + a.y*a.y) + (a.z*a.z + a.w*a.w)
                + (b.x*b.x + b.y*b.y) + (b.z*b.z + b.w*b.w);
        #pragma unroll
        for (int off = 1; off < 16; off <<= 1) s += __shfl_xor(s, off, 16);
        if ((t & 15) == 0) qsqg[r] = s;
    }
}

// ---------------- p1: bf16x3 MFMA distance matrix ----------------
// block = 256 q x 128 k, 512 threads (8 waves), wave = 32q x 128k.
__global__ __launch_bounds__(512, 2)
void p1_mfma(const float* __restrict__ qkey, const float* __restrict__ keys,
             const float* __restrict__ qsqg, float* __restrict__ dist,
             int q0, int nq)
{
    __shared__ __align__(16) unsigned short khs[KT2 * DIM];  // 32 KB, XOR-swizzled
    __shared__ __align__(16) unsigned short kls[KT2 * DIM];  // 32 KB
    __shared__ float ksq_s[KT2];
    __shared__ float qsq_s[BQ];

    const int tid   = threadIdx.x;
    const int kbase = blockIdx.x * KT2;

    if (tid < BQ) qsq_s[tid] = qsqg[tid];

    // stage keys fp32 -> bf16 hi/lo in LDS (swizzled) + ksq via shfl-reduce
    #pragma unroll
    for (int p = 0; p < 4; ++p) {
        int flat = p * 4096 + tid * 8;
        int rr = flat >> 7;          // key row in tile
        int d0 = flat & 127;
        const float* src = keys + (((size_t)(kbase + rr)) << 7) + d0;
        float4 a = *(const float4*)src, b = *(const float4*)(src + 4);
        float xs[8] = { a.x, a.y, a.z, a.w, b.x, b.y, b.z, b.w };
        bf16x8 hv, lv;
        float sq = 0.f;
        #pragma unroll
        for (int i = 0; i < 8; ++i) {
            unsigned short h = f2bf(xs[i]);
            hv[i] = (short)h;
            lv[i] = (short)f2bf(xs[i] - bf2f(h));
            sq = fmaf(xs[i], xs[i], sq);
        }
        unsigned byte = (unsigned)((rr << 8) + (d0 << 1));
        byte ^= (unsigned)((rr & 7) << 4);                    // T2/G4 swizzle
        *(bf16x8*)((char*)khs + byte) = hv;
        *(bf16x8*)((char*)kls + byte) = lv;
        #pragma unroll
        for (int off = 1; off < 16; off <<= 1) sq += __shfl_xor(sq, off, 16);
        if ((tid & 15) == 0) ksq_s[rr] = sq;
    }

    // Q fragments in registers (global reads, qkey is L2-hot: 128 KB total)
    const int lane = tid & 63, wv = tid >> 6;
    const int qb0 = wv * 32;
    const int fr = lane & 15, fg = lane >> 4;
    bf16x8 qh[2][4], ql[2][4];
    #pragma unroll
    for (int qf = 0; qf < 2; ++qf)
        #pragma unroll
        for (int s = 0; s < 4; ++s) {
            const float* qp = qkey + ((size_t)(qb0 + qf * 16 + fr) << 7) + s * 32 + fg * 8;
            float4 a = *(const float4*)qp, b = *(const float4*)(qp + 4);
            float xs[8] = { a.x, a.y, a.z, a.w, b.x, b.y, b.z, b.w };
            bf16x8 hv, lv;
            #pragma unroll
            for (int i = 0; i < 8; ++i) {
                unsigned short h = f2bf(xs[i]);
                hv[i] = (short)h;
                lv[i] = (short)f2bf(xs[i] - bf2f(h));
            }
            qh[qf][s] = hv; ql[qf][s] = lv;
        }

    f32x4 acc[2][8];
    #pragma unroll
    for (int qf = 0; qf < 2; ++qf)
        #pragma unroll
        for (int kf = 0; kf < 8; ++kf) acc[qf][kf] = f32x4{0.f, 0.f, 0.f, 0.f};

    __syncthreads();

    // main MFMA loop: dot = qh.kh + ql.kh + qh.kl  (lo.lo dropped, ~4e-5 err)
    #pragma unroll 1
    for (int s = 0; s < 4; ++s) {
        #pragma unroll
        for (int kf = 0; kf < 8; ++kf) {
            int krow = kf * 16 + fr;
            int d0   = s * 32 + fg * 8;
            unsigned byte = ((unsigned)((krow << 8) + (d0 << 1))) ^ (unsigned)((krow & 7) << 4);
            bf16x8 bh = *(bf16x8*)((char*)khs + byte);
            bf16x8 bl = *(bf16x8*)((char*)kls + byte);
            #pragma unroll
            for (int qf = 0; qf < 2; ++qf) {
                acc[qf][kf] = __builtin_amdgcn_mfma_f32_16x16x32_bf16(qh[qf][s], bh, acc[qf][kf], 0, 0, 0);
                acc[qf][kf] = __builtin_amdgcn_mfma_f32_16x16x32_bf16(ql[qf][s], bh, acc[qf][kf], 0, 0, 0);
                acc[qf][kf] = __builtin_amdgcn_mfma_f32_16x16x32_bf16(qh[qf][s], bl, acc[qf][kf], 0, 0, 0);
            }
        }
    }

    // epilogue: dist = qsq + ksq - 2*dot, clamped. C/D: col=lane&15, row=(lane>>4)*4+reg
    #pragma unroll
    for (int qf = 0; qf < 2; ++qf) {
        #pragma unroll
        for (int kf = 0; kf < 8; ++kf) {
            int k = kbase + kf * 16 + fr;
            float kq = ksq_s[kf * 16 + fr];
            f32x4 a = acc[qf][kf];
            #pragma unroll
            for (int rg = 0; rg < 4; ++rg) {
                int q = qb0 + qf * 16 + fg * 4 + rg;
                int qrel = q - q0;
                if (qrel >= 0 && qrel < nq) {
                    float dv = fmaxf(qsq_s[q] + kq - 2.f * a[rg], 0.f);
                    dist[(size_t)qrel * NK + k] = dv;
                }
            }
        }
    }
}

// ---------------- p2: radix-select K-th smallest + weighted mean ----------------
__global__ __launch_bounds__(1024, 1)
void p2_select(const float* __restrict__ dist,
               const float* __restrict__ values,
               const int* __restrict__ pK,
               float* __restrict__ out)
{
    const int tid  = threadIdx.x;
    const int lane = tid & 63;
    const int wid  = tid >> 6;
    const float4* row4 = (const float4*)(dist + (size_t)blockIdx.x * NK);

    int K = *pK; if (K < 1) K = 1; if (K > NK) K = NK;

    __shared__ int   hist[NB];       // 32 KB
    __shared__ uint2 list[CAP];      // 16 KB
    __shared__ int   lcount, s_bb, s_cb;
    __shared__ int   iscan[16];
    __shared__ float fred[48];

    for (int i = tid; i < NB; i += 1024) hist[i] = 0;
    if (tid == 0) { lcount = 0; s_bb = NB - 1; s_cb = 0; }
    __syncthreads();

    for (int i = 0; i < NK / 4096; ++i) {
        float4 v = row4[tid + 1024 * i];
        atomicAdd(&hist[__float_as_uint(v.x) >> SHIFT], 1);
        atomicAdd(&hist[__float_as_uint(v.y) >> SHIFT], 1);
        atomicAdd(&hist[__float_as_uint(v.z) >> SHIFT], 1);
        atomicAdd(&hist[__float_as_uint(v.w) >> SHIFT], 1);
    }
    __syncthreads();

    int h[8], s = 0;
    #pragma unroll
    for (int b = 0; b < 8; ++b) { h[b] = hist[tid * 8 + b]; s += h[b]; }
    int incl = s;
    #pragma unroll
    for (int off = 1; off < 64; off <<= 1) {
        int t = __shfl_up(incl, off, 64);
        if (lane >= off) incl += t;
    }
    if (lane == 63) iscan[wid] = incl;
    __syncthreads();
    if (tid == 0) { int c = 0; for (int w = 0; w < 16; ++w) { int t = iscan[w]; iscan[w] = c; c += t; } }
    __syncthreads();
    int base = iscan[wid] + (incl - s);
    if (base < K && K <= base + s) {
        int c = base;
        #pragma unroll
        for (int b = 0; b < 8; ++b) {
            if (c < K && c + h[b] >= K) { s_bb = tid * 8 + b; s_cb = c; }
            c += h[b];
        }
    }
    __syncthreads();
    const int bb = s_bb, cbelow = s_cb, R = K - cbelow, CEall = hist[bb];

    float sw = 0.f, swv = 0.f, seva = 0.f;
    for (int i = 0; i < NK / 4096; ++i) {
        float4 v = row4[tid + 1024 * i];
        int n0 = (tid + 1024 * i) * 4;
        float dd[4] = { v.x, v.y, v.z, v.w };
        #pragma unroll
        for (int c = 0; c < 4; ++c) {
            unsigned bts = __float_as_uint(dd[c]);
            int bin = (int)(bts >> SHIFT);
            if (bin < bb) {
                float w = 1.f / (dd[c] + DELTA);
                float vv = values[n0 + c];
                sw += w; swv = fmaf(w, vv, swv);
            } else if (bin == bb) {
                float vv = values[n0 + c];
                seva += vv;
                int sl = atomicAdd(&lcount, 1);
                if (sl < CAP) list[sl] = make_uint2(bts, __float_as_uint(vv));
            }
        }
    }
    #pragma unroll
    for (int off = 32; off; off >>= 1) {
        sw   += __shfl_down(sw,   off, 64);
        swv  += __shfl_down(swv,  off, 64);
        seva += __shfl_down(seva, off, 64);
    }
    if (lane == 0) { fred[wid] = sw; fred[16 + wid] = swv; fred[32 + wid] = seva; }
    __syncthreads();

    if (wid == 0) {
        float SW = 0.f, SWV = 0.f, SEVA = 0.f;
        for (int w = 0; w < 16; ++w) { SW += fred[w]; SWV += fred[16 + w]; SEVA += fred[32 + w]; }
        const int L = lcount;
        double num, den;
        if (L <= CAP) {
            unsigned lo = ((unsigned)bb) << SHIFT;
            unsigned hi = lo + ((1u << SHIFT) - 1u);
            while (lo < hi) {
                unsigned mid = lo + ((hi - lo) >> 1);
                int c = 0;
                for (int i = lane; i < L; i += 64) c += (list[i].x <= mid) ? 1 : 0;
                #pragma unroll
                for (int off = 32; off; off >>= 1) c += __shfl_xor(c, off, 64);
                if (c >= R) hi = mid; else lo = mid + 1;
            }
            const unsigned T = lo;
            int cl2 = 0, ce = 0;
            double swl = 0.0, swvl = 0.0, sevt = 0.0;
            for (int i = lane; i < L; i += 64) {
                unsigned b = list[i].x;
                float vv = __uint_as_float(list[i].y);
                if (b < T) {
                    double w = 1.0 / ((double)__uint_as_float(b) + (double)DELTA);
                    cl2 += 1; swl += w; swvl += w * (double)vv;
                } else if (b == T) { ce += 1; sevt += (double)vv; }
            }
            #pragma unroll
            for (int off = 32; off; off >>= 1) {
                cl2  += __shfl_xor(cl2,  off, 64);
                ce   += __shfl_xor(ce,   off, 64);
                swl  += __shfl_xor(swl,  off, 64);
                swvl += __shfl_xor(swvl, off, 64);
                sevt += __shfl_xor(sevt, off, 64);
            }
            const int need = R - cl2;
            double wT = 1.0 / ((double)__uint_as_float(T) + (double)DELTA);
            num = (double)SWV + swvl + wT * ((double)need / (double)ce) * sevt;
            den = (double)SW  + swl  + wT * (double)need;
        } else {
            double wT = 1.0 / ((double)__uint_as_float(((unsigned)bb) << SHIFT) + (double)DELTA);
            num = (double)SWV + wT * ((double)R / (double)CEall) * (double)SEVA;
            den = (double)SW  + wT * (double)R;
        }
        if (lane == 0) out[blockIdx.x] = (float)(num / den);
    }
}

extern "C" void kernel_launch(void* const* d_in, const int* in_sizes, int n_in,
                              void* d_out, int out_size, void* d_ws, size_t ws_size,
                              hipStream_t stream)
{
    const float* qkey   = (const float*)d_in[0];
    const float* keys   = (const float*)d_in[1];
    const float* values = (const float*)d_in[2];
    const int*   pK     = (const int*)d_in[3];
    float* out  = (float*)d_out;

    float* qsqg = (float*)d_ws;                 // 1 KB (padded to 4 KB)
    float* dist = (float*)d_ws + 1024;

    p0_qsq<<<dim3(1), dim3(256), 0, stream>>>(qkey, qsqg);

    const size_t rowb = (size_t)NK * sizeof(float);
    const size_t avail = ws_size - 4096;
    int slabQ = (avail >= (size_t)BQ * rowb) ? BQ : (int)(avail / rowb);
    if (slabQ < 1) slabQ = 1;                   // ws guaranteed bigger in practice

    for (int q0 = 0; q0 < BQ; q0 += slabQ) {
        int nq = BQ - q0; if (nq > slabQ) nq = slabQ;
        p1_mfma<<<dim3(NCH2), dim3(512), 0, stream>>>(qkey, keys, qsqg, dist, q0, nq);
        p2_select<<<dim3(nq), dim3(1024), 0, stream>>>(dist, values, pK, out + q0);
    }
}

// Round 4
// 126.151 us; speedup vs baseline: 5.6356x; 5.6356x over previous
//
#include <hip/hip_runtime.h>

#define BQ 256
#define NK 131072
#define DIM 128
#define KT2 128                  // keys per block (p1)
#define NCH2 (NK / KT2)          // 1024 blocks
#define DELTA 1e-3f

#define NB 8192                  // radix bins (float bits >> 18)
#define SHIFT 18
#define CAP 2048

typedef __attribute__((ext_vector_type(8))) short bf16x8;
typedef __attribute__((ext_vector_type(4))) float f32x4;

__device__ __forceinline__ unsigned short f2bf(float x) {
    unsigned u = __float_as_uint(x);
    u += 0x7fffu + ((u >> 16) & 1u);
    return (unsigned short)(u >> 16);
}
__device__ __forceinline__ float bf2f(unsigned short h) {
    return __uint_as_float(((unsigned)h) << 16);
}

// ---------------- p0: query squared norms ----------------
__global__ __launch_bounds__(256, 4)
void p0_qsq(const float* __restrict__ qkey, float* __restrict__ qsqg)
{
    const int t = threadIdx.x;
    #pragma unroll 1
    for (int p = 0; p < 16; ++p) {
        int r  = p * 16 + (t >> 4);
        int d0 = (t & 15) * 8;
        const float* src = qkey + (r << 7) + d0;
        float4 a = *(const float4*)src, b = *(const float4*)(src + 4);
        float s = (a.x*a.x + a.y*a.y) + (a.z*a.z + a.w*a.w)
                + (b.x*b.x + b.y*b.y) + (b.z*b.z + b.w*b.w);
        #pragma unroll
        for (int off = 1; off < 16; off <<= 1) s += __shfl_xor(s, off, 16);
        if ((t & 15) == 0) qsqg[r] = s;
    }
}

// ---------------- p1: bf16x3 MFMA distance matrix ----------------
// block = 256 q x 128 k, 512 threads (8 waves), wave = 32q x 128k.
// FULLY UNROLLED main loop: all fragment-array indices compile-time (rule #20).
__global__ __launch_bounds__(512, 2)
void p1_mfma(const float* __restrict__ qkey, const float* __restrict__ keys,
             const float* __restrict__ qsqg, float* __restrict__ dist,
             int q0, int nq)
{
    __shared__ __align__(16) unsigned short khs[KT2 * DIM];  // 32 KB, XOR-swizzled
    __shared__ __align__(16) unsigned short kls[KT2 * DIM];  // 32 KB
    __shared__ float ksq_s[KT2];
    __shared__ float qsq_s[BQ];

    const int tid   = threadIdx.x;
    const int kbase = blockIdx.x * KT2;

    if (tid < BQ) qsq_s[tid] = qsqg[tid];

    // stage keys fp32 -> bf16 hi/lo in LDS (swizzled) + ksq via shfl-reduce
    #pragma unroll
    for (int p = 0; p < 4; ++p) {
        int flat = p * 4096 + tid * 8;
        int rr = flat >> 7;          // key row in tile
        int d0 = flat & 127;
        const float* src = keys + (((size_t)(kbase + rr)) << 7) + d0;
        float4 a = *(const float4*)src, b = *(const float4*)(src + 4);
        float xs0 = a.x, xs1 = a.y, xs2 = a.z, xs3 = a.w;
        float xs4 = b.x, xs5 = b.y, xs6 = b.z, xs7 = b.w;
        bf16x8 hv, lv;
        unsigned short h;
        h = f2bf(xs0); hv[0] = (short)h; lv[0] = (short)f2bf(xs0 - bf2f(h));
        h = f2bf(xs1); hv[1] = (short)h; lv[1] = (short)f2bf(xs1 - bf2f(h));
        h = f2bf(xs2); hv[2] = (short)h; lv[2] = (short)f2bf(xs2 - bf2f(h));
        h = f2bf(xs3); hv[3] = (short)h; lv[3] = (short)f2bf(xs3 - bf2f(h));
        h = f2bf(xs4); hv[4] = (short)h; lv[4] = (short)f2bf(xs4 - bf2f(h));
        h = f2bf(xs5); hv[5] = (short)h; lv[5] = (short)f2bf(xs5 - bf2f(h));
        h = f2bf(xs6); hv[6] = (short)h; lv[6] = (short)f2bf(xs6 - bf2f(h));
        h = f2bf(xs7); hv[7] = (short)h; lv[7] = (short)f2bf(xs7 - bf2f(h));
        float sq = (xs0*xs0 + xs1*xs1) + (xs2*xs2 + xs3*xs3)
                 + (xs4*xs4 + xs5*xs5) + (xs6*xs6 + xs7*xs7);
        unsigned byte = (unsigned)((rr << 8) + (d0 << 1));
        byte ^= (unsigned)((rr & 7) << 4);                    // T2/G4 swizzle
        *(bf16x8*)((char*)khs + byte) = hv;
        *(bf16x8*)((char*)kls + byte) = lv;
        #pragma unroll
        for (int off = 1; off < 16; off <<= 1) sq += __shfl_xor(sq, off, 16);
        if ((tid & 15) == 0) ksq_s[rr] = sq;
    }

    // Q fragments in registers (global reads, qkey is L2-hot: 128 KB total)
    const int lane = tid & 63, wv = tid >> 6;
    const int qb0 = wv * 32;
    const int fr = lane & 15, fg = lane >> 4;
    bf16x8 qh[2][4], ql[2][4];
    #pragma unroll
    for (int qf = 0; qf < 2; ++qf)
        #pragma unroll
        for (int s = 0; s < 4; ++s) {
            const float* qp = qkey + ((size_t)(qb0 + qf * 16 + fr) << 7) + s * 32 + fg * 8;
            float4 a = *(const float4*)qp, b = *(const float4*)(qp + 4);
            float x0 = a.x, x1 = a.y, x2 = a.z, x3 = a.w;
            float x4 = b.x, x5 = b.y, x6 = b.z, x7 = b.w;
            bf16x8 hv, lv;
            unsigned short h;
            h = f2bf(x0); hv[0] = (short)h; lv[0] = (short)f2bf(x0 - bf2f(h));
            h = f2bf(x1); hv[1] = (short)h; lv[1] = (short)f2bf(x1 - bf2f(h));
            h = f2bf(x2); hv[2] = (short)h; lv[2] = (short)f2bf(x2 - bf2f(h));
            h = f2bf(x3); hv[3] = (short)h; lv[3] = (short)f2bf(x3 - bf2f(h));
            h = f2bf(x4); hv[4] = (short)h; lv[4] = (short)f2bf(x4 - bf2f(h));
            h = f2bf(x5); hv[5] = (short)h; lv[5] = (short)f2bf(x5 - bf2f(h));
            h = f2bf(x6); hv[6] = (short)h; lv[6] = (short)f2bf(x6 - bf2f(h));
            h = f2bf(x7); hv[7] = (short)h; lv[7] = (short)f2bf(x7 - bf2f(h));
            qh[qf][s] = hv; ql[qf][s] = lv;
        }

    f32x4 acc[2][8];
    #pragma unroll
    for (int qf = 0; qf < 2; ++qf)
        #pragma unroll
        for (int kf = 0; kf < 8; ++kf) acc[qf][kf] = f32x4{0.f, 0.f, 0.f, 0.f};

    __syncthreads();

    // main MFMA loop, FULLY unrolled: dot = qh.kh + ql.kh + qh.kl
    #pragma unroll
    for (int s = 0; s < 4; ++s) {
        #pragma unroll
        for (int kf = 0; kf < 8; ++kf) {
            const int krow = kf * 16 + fr;
            const int d0   = s * 32 + fg * 8;
            unsigned byte = ((unsigned)((krow << 8) + (d0 << 1))) ^ (unsigned)((krow & 7) << 4);
            bf16x8 bh = *(bf16x8*)((char*)khs + byte);
            bf16x8 bl = *(bf16x8*)((char*)kls + byte);
            #pragma unroll
            for (int qf = 0; qf < 2; ++qf) {
                acc[qf][kf] = __builtin_amdgcn_mfma_f32_16x16x32_bf16(qh[qf][s], bh, acc[qf][kf], 0, 0, 0);
                acc[qf][kf] = __builtin_amdgcn_mfma_f32_16x16x32_bf16(ql[qf][s], bh, acc[qf][kf], 0, 0, 0);
                acc[qf][kf] = __builtin_amdgcn_mfma_f32_16x16x32_bf16(qh[qf][s], bl, acc[qf][kf], 0, 0, 0);
            }
        }
    }

    // epilogue: dist = qsq + ksq - 2*dot, clamped. C/D: col=lane&15, row=(lane>>4)*4+reg
    #pragma unroll
    for (int qf = 0; qf < 2; ++qf) {
        #pragma unroll
        for (int kf = 0; kf < 8; ++kf) {
            int k = kbase + kf * 16 + fr;
            float kq = ksq_s[kf * 16 + fr];
            f32x4 a = acc[qf][kf];
            #pragma unroll
            for (int rg = 0; rg < 4; ++rg) {
                int q = qb0 + qf * 16 + fg * 4 + rg;
                int qrel = q - q0;
                if (qrel >= 0 && qrel < nq) {
                    float dv = fmaxf(qsq_s[q] + kq - 2.f * a[rg], 0.f);
                    dist[(size_t)qrel * NK + k] = dv;
                }
            }
        }
    }
}

// ---------------- p2: radix-select K-th smallest + weighted mean ----------------
__global__ __launch_bounds__(1024, 1)
void p2_select(const float* __restrict__ dist,
               const float* __restrict__ values,
               const int* __restrict__ pK,
               float* __restrict__ out)
{
    const int tid  = threadIdx.x;
    const int lane = tid & 63;
    const int wid  = tid >> 6;
    const float4* row4 = (const float4*)(dist + (size_t)blockIdx.x * NK);

    int K = *pK; if (K < 1) K = 1; if (K > NK) K = NK;

    __shared__ int   hist[NB];       // 32 KB
    __shared__ uint2 list[CAP];      // 16 KB
    __shared__ int   lcount, s_bb, s_cb;
    __shared__ int   iscan[16];
    __shared__ float fred[48];

    for (int i = tid; i < NB; i += 1024) hist[i] = 0;
    if (tid == 0) { lcount = 0; s_bb = NB - 1; s_cb = 0; }
    __syncthreads();

    for (int i = 0; i < NK / 4096; ++i) {
        float4 v = row4[tid + 1024 * i];
        atomicAdd(&hist[__float_as_uint(v.x) >> SHIFT], 1);
        atomicAdd(&hist[__float_as_uint(v.y) >> SHIFT], 1);
        atomicAdd(&hist[__float_as_uint(v.z) >> SHIFT], 1);
        atomicAdd(&hist[__float_as_uint(v.w) >> SHIFT], 1);
    }
    __syncthreads();

    int h[8], s = 0;
    #pragma unroll
    for (int b = 0; b < 8; ++b) { h[b] = hist[tid * 8 + b]; s += h[b]; }
    int incl = s;
    #pragma unroll
    for (int off = 1; off < 64; off <<= 1) {
        int t = __shfl_up(incl, off, 64);
        if (lane >= off) incl += t;
    }
    if (lane == 63) iscan[wid] = incl;
    __syncthreads();
    if (tid == 0) { int c = 0; for (int w = 0; w < 16; ++w) { int t = iscan[w]; iscan[w] = c; c += t; } }
    __syncthreads();
    int base = iscan[wid] + (incl - s);
    if (base < K && K <= base + s) {
        int c = base;
        #pragma unroll
        for (int b = 0; b < 8; ++b) {
            if (c < K && c + h[b] >= K) { s_bb = tid * 8 + b; s_cb = c; }
            c += h[b];
        }
    }
    __syncthreads();
    const int bb = s_bb, cbelow = s_cb, R = K - cbelow, CEall = hist[bb];

    float sw = 0.f, swv = 0.f, seva = 0.f;
    for (int i = 0; i < NK / 4096; ++i) {
        float4 v = row4[tid + 1024 * i];
        int n0 = (tid + 1024 * i) * 4;
        float dd[4] = { v.x, v.y, v.z, v.w };
        #pragma unroll
        for (int c = 0; c < 4; ++c) {
            unsigned bts = __float_as_uint(dd[c]);
            int bin = (int)(bts >> SHIFT);
            if (bin < bb) {
                float w = 1.f / (dd[c] + DELTA);
                float vv = values[n0 + c];
                sw += w; swv = fmaf(w, vv, swv);
            } else if (bin == bb) {
                float vv = values[n0 + c];
                seva += vv;
                int sl = atomicAdd(&lcount, 1);
                if (sl < CAP) list[sl] = make_uint2(bts, __float_as_uint(vv));
            }
        }
    }
    #pragma unroll
    for (int off = 32; off; off >>= 1) {
        sw   += __shfl_down(sw,   off, 64);
        swv  += __shfl_down(swv,  off, 64);
        seva += __shfl_down(seva, off, 64);
    }
    if (lane == 0) { fred[wid] = sw; fred[16 + wid] = swv; fred[32 + wid] = seva; }
    __syncthreads();

    if (wid == 0) {
        float SW = 0.f, SWV = 0.f, SEVA = 0.f;
        for (int w = 0; w < 16; ++w) { SW += fred[w]; SWV += fred[16 + w]; SEVA += fred[32 + w]; }
        const int L = lcount;
        double num, den;
        if (L <= CAP) {
            unsigned lo = ((unsigned)bb) << SHIFT;
            unsigned hi = lo + ((1u << SHIFT) - 1u);
            while (lo < hi) {
                unsigned mid = lo + ((hi - lo) >> 1);
                int c = 0;
                for (int i = lane; i < L; i += 64) c += (list[i].x <= mid) ? 1 : 0;
                #pragma unroll
                for (int off = 32; off; off >>= 1) c += __shfl_xor(c, off, 64);
                if (c >= R) hi = mid; else lo = mid + 1;
            }
            const unsigned T = lo;
            int cl2 = 0, ce = 0;
            double swl = 0.0, swvl = 0.0, sevt = 0.0;
            for (int i = lane; i < L; i += 64) {
                unsigned b = list[i].x;
                float vv = __uint_as_float(list[i].y);
                if (b < T) {
                    double w = 1.0 / ((double)__uint_as_float(b) + (double)DELTA);
                    cl2 += 1; swl += w; swvl += w * (double)vv;
                } else if (b == T) { ce += 1; sevt += (double)vv; }
            }
            #pragma unroll
            for (int off = 32; off; off >>= 1) {
                cl2  += __shfl_xor(cl2,  off, 64);
                ce   += __shfl_xor(ce,   off, 64);
                swl  += __shfl_xor(swl,  off, 64);
                swvl += __shfl_xor(swvl, off, 64);
                sevt += __shfl_xor(sevt, off, 64);
            }
            const int need = R - cl2;
            double wT = 1.0 / ((double)__uint_as_float(T) + (double)DELTA);
            num = (double)SWV + swvl + wT * ((double)need / (double)ce) * sevt;
            den = (double)SW  + swl  + wT * (double)need;
        } else {
            double wT = 1.0 / ((double)__uint_as_float(((unsigned)bb) << SHIFT) + (double)DELTA);
            num = (double)SWV + wT * ((double)R / (double)CEall) * (double)SEVA;
            den = (double)SW  + wT * (double)R;
        }
        if (lane == 0) out[blockIdx.x] = (float)(num / den);
    }
}

extern "C" void kernel_launch(void* const* d_in, const int* in_sizes, int n_in,
                              void* d_out, int out_size, void* d_ws, size_t ws_size,
                              hipStream_t stream)
{
    const float* qkey   = (const float*)d_in[0];
    const float* keys   = (const float*)d_in[1];
    const float* values = (const float*)d_in[2];
    const int*   pK     = (const int*)d_in[3];
    float* out  = (float*)d_out;

    float* qsqg = (float*)d_ws;                 // 1 KB (padded to 4 KB)
    float* dist = (float*)d_ws + 1024;

    p0_qsq<<<dim3(1), dim3(256), 0, stream>>>(qkey, qsqg);

    const size_t rowb = (size_t)NK * sizeof(float);
    const size_t avail = ws_size - 4096;
    int slabQ = (avail >= (size_t)BQ * rowb) ? BQ : (int)(avail / rowb);
    if (slabQ < 1) slabQ = 1;

    for (int q0 = 0; q0 < BQ; q0 += slabQ) {
        int nq = BQ - q0; if (nq > slabQ) nq = slabQ;
        p1_mfma<<<dim3(NCH2), dim3(512), 0, stream>>>(qkey, keys, qsqg, dist, q0, nq);
        p2_select<<<dim3(nq), dim3(1024), 0, stream>>>(dist, values, pK, out + q0);
    }
}